// Round 8
// baseline (217.030 us; speedup 1.0000x reference)
//
#include <hip/hip_runtime.h>
#include <hip/hip_bf16.h>
#include <cstdint>

// Problem dims
#define Bn 8
#define Cn 256
#define Hn 48
#define NUM_MEM 9
#define WSZ 16
#define Sn 128
#define Dn 65536   // 16*16*256
#define KTOP 5
#define NDC 64     // d-chunks (1024 floats = 4KB each)

typedef float f32x4 __attribute__((ext_vector_type(4)));

// ---------------- Phase A: x (B,C,H,W) -> q (B,M,D), D = (i*16+j)*256 + c ----
__global__ __launch_bounds__(256) void k_x2q(const float* __restrict__ x,
                                             float* __restrict__ q) {
    const int h = blockIdx.x;          // 0..47
    const int b = blockIdx.y;          // 0..7
    const int gh = h >> 4, i = h & 15;
    __shared__ float tile[Cn * Hn];    // [c][w], 48KB
    const float* xp = x + (size_t)b * Cn * Hn * Hn + (size_t)h * Hn;
    for (int o = threadIdx.x; o < Cn * Hn; o += blockDim.x) {
        int c = o / Hn, w = o - c * Hn;
        tile[o] = xp[(size_t)c * Hn * Hn + w];
    }
    __syncthreads();
    for (int gw = 0; gw < 3; ++gw) {
        float* qp = q + (size_t)(b * NUM_MEM + gh * 3 + gw) * Dn + i * (WSZ * Cn);
        for (int l = threadIdx.x; l < WSZ * Cn; l += blockDim.x) {
            int j = l >> 8, c = l & 255;
            qp[l] = tile[c * Hn + gw * WSZ + j];
        }
    }
}

// ---------------- Phase B: single-shot partial dots, 4KB/row NT reads -------
// block = (dc, m, sg); wave owns 4 rows (e = sg>>3, s = (sg&7)*16 + wave*4+r),
// d-range [dc*1024, +1024). Per row: 4 back-to-back NT 1KB wave-loads = 4KB
// contiguous DRAM burst (vs 2KB in round 7) -- tests the granule hypothesis.
// Accumulators persist across the two 512-float halves; one reduce at end.
// ap[dc][(e*8+b)*9+m][s] = partial dot over the 1024-float chunk.
__global__ __launch_bounds__(256) void k_att7(const float* __restrict__ q,
                                              const float* __restrict__ mem1,
                                              const float* __restrict__ mem2,
                                              float* __restrict__ ap) {
    const int dc = blockIdx.x;     // 0..63
    const int mw = blockIdx.y;     // 0..8
    const int sg = blockIdx.z;     // 0..15
    const int e  = sg >> 3;
    const int lane = threadIdx.x & 63, wave = threadIdx.x >> 6;
    const int s0 = (sg & 7) * 16 + wave * 4;        // first of 4 s-rows

    const f32x4* mem4 = (const f32x4*)(e ? mem2 : mem1);
    const f32x4* q4   = (const f32x4*)q;
    const int off = dc * 256 + lane;                // f32x4 offset of slice 0

    // 16 NT loads (4 rows x 4 slices), issued 4-contiguous per row
    f32x4 MA[4][2], MB[4][2];
#pragma unroll
    for (int r = 0; r < 4; ++r) {
        const f32x4* mp = mem4 + (size_t)(mw * Sn + s0 + r) * (Dn / 4) + off;
        MA[r][0] = __builtin_nontemporal_load(mp);
        MA[r][1] = __builtin_nontemporal_load(mp + 64);
        MB[r][0] = __builtin_nontemporal_load(mp + 128);
        MB[r][1] = __builtin_nontemporal_load(mp + 192);
    }

    float a[32];                                    // a[r*8+b]
#pragma unroll
    for (int i = 0; i < 32; ++i) a[i] = 0.f;

    // half A (slices 0,64), then half B (slices 128,192); q in 4-batch groups
#pragma unroll
    for (int half = 0; half < 2; ++half) {
        f32x4 Q[4][2];
#pragma unroll
        for (int b = 0; b < 4; ++b) {
            const f32x4* qp = q4 + (size_t)((half * 4 + b) * NUM_MEM + mw) * (Dn / 4) + off;
            Q[b][0] = qp[0];
            Q[b][1] = qp[64];
        }
#pragma unroll
        for (int r = 0; r < 4; ++r)
#pragma unroll
            for (int b = 0; b < 4; ++b) {
                const int bi = half * 4 + b;
                float acc = a[r * 8 + bi];
#pragma unroll
                for (int k = 0; k < 4; ++k)
                    acc += MA[r][0][k] * Q[b][0][k] + MA[r][1][k] * Q[b][1][k];
                a[r * 8 + bi] = acc;
            }
    }
#pragma unroll
    for (int half = 0; half < 2; ++half) {
        f32x4 Q[4][2];
#pragma unroll
        for (int b = 0; b < 4; ++b) {
            const f32x4* qp = q4 + (size_t)((half * 4 + b) * NUM_MEM + mw) * (Dn / 4) + off;
            Q[b][0] = qp[128];
            Q[b][1] = qp[192];
        }
#pragma unroll
        for (int r = 0; r < 4; ++r)
#pragma unroll
            for (int b = 0; b < 4; ++b) {
                const int bi = half * 4 + b;
                float acc = a[r * 8 + bi];
#pragma unroll
                for (int k = 0; k < 4; ++k)
                    acc += MB[r][0][k] * Q[b][0][k] + MB[r][1][k] * Q[b][1][k];
                a[r * 8 + bi] = acc;
            }
    }

    // fold-reduce: 32 values across 64 lanes (verified rounds 3-7)
#pragma unroll
    for (int k = 0; k < 5; ++k) {
        const int mk = 1 << k;
        const bool up = (lane & mk) != 0;
#pragma unroll
        for (int j = 0; j < (32 >> (k + 1)); ++j) {
            float lo = a[2 * j], hi = a[2 * j + 1];
            float mine = up ? hi : lo;
            float oth  = __shfl_xor(up ? lo : hi, mk, 64);
            a[j] = mine + oth;
        }
    }
    float rsum = a[0] + __shfl_xor(a[0], 32, 64);
    if (lane < 32) {
        const int b = lane & 7, r = (lane >> 3) & 3;
        ap[((size_t)dc * 144 + (size_t)(e * 8 + b) * 9 + mw) * Sn + (s0 + r)] = rsum;
    }
}

// ---------------- Phase C: nd-reduce + softmax + top-5 + shrink + L1 --------
__global__ __launch_bounds__(128) void k_smax(const float* __restrict__ ap,
                                              float* __restrict__ w) {
    const int row = blockIdx.x;        // 0..143  = (e*8+b)*9+m
    const int t = threadIdx.x;         // 0..127
    __shared__ float sf[Sn];
    __shared__ unsigned long long sk[Sn];

    float v = 0.f;
#pragma unroll 8
    for (int nd = 0; nd < NDC; ++nd)
        v += ap[((size_t)nd * 144 + row) * Sn + t];

    sf[t] = v; __syncthreads();
    for (int s = 64; s > 0; s >>= 1) { if (t < s) sf[t] = fmaxf(sf[t], sf[t + s]); __syncthreads(); }
    float mx = sf[0]; __syncthreads();

    float e = expf(v - mx);
    sf[t] = e; __syncthreads();
    for (int s = 64; s > 0; s >>= 1) { if (t < s) sf[t] += sf[t + s]; __syncthreads(); }
    float sum = sf[0]; __syncthreads();
    float y = e / sum;                 // softmax (y > 0)

    // 5 iterations of packed (value,index) argmax-with-exclusion -> 5th largest
    bool alive = true;
    float thres = 0.f;
    unsigned int ybits = __float_as_uint(y);   // y>0 -> bits monotonic
    for (int it = 0; it < KTOP; ++it) {
        sk[t] = alive ? ((((unsigned long long)ybits) << 32) | (unsigned)t) : 0ull;
        __syncthreads();
        for (int s = 64; s > 0; s >>= 1) {
            if (t < s) { if (sk[t + s] > sk[t]) sk[t] = sk[t + s]; }
            __syncthreads();
        }
        unsigned long long kmax = sk[0];
        __syncthreads();
        if ((unsigned)(kmax & 0xffffffffull) == (unsigned)t) alive = false;
        thres = __uint_as_float((unsigned)(kmax >> 32));
    }

    float d   = y - thres;
    float num = fmaxf(d, 0.f) * y;
    float yh  = num / (fabsf(d) + 1e-12f);     // exact reference formula

    sf[t] = yh; __syncthreads();
    for (int s = 64; s > 0; s >>= 1) { if (t < s) sf[t] += sf[t + s]; __syncthreads(); }
    float l1 = sf[0];
    w[(size_t)row * Sn + t] = yh / fmaxf(l1, 1e-12f);
}

// ---------------- Phase D: acc[b,m,:] = sum_s w1*mem1 + w2*mem2 -------------
__global__ __launch_bounds__(256) void k_acc(const float* __restrict__ w,
                                             const float* __restrict__ mem1,
                                             const float* __restrict__ mem2,
                                             float* __restrict__ acc) {
    const int chunk = blockIdx.x;      // 0..15 (4096 floats each)
    const int m     = blockIdx.y;      // 0..8
    const int b     = blockIdx.z;      // 0..7
    __shared__ int   nz[2];
    __shared__ int   idx[2][16];
    __shared__ float wv[2][16];
    if (threadIdx.x < 2) nz[threadIdx.x] = 0;
    __syncthreads();
    {
        int eidx = threadIdx.x >> 7;           // 0 or 1
        int s    = threadIdx.x & 127;
        float ww = w[((size_t)(eidx * Bn + b) * NUM_MEM + m) * Sn + s];
        if (ww != 0.f) {
            int p = atomicAdd(&nz[eidx], 1);
            if (p < 16) { idx[eidx][p] = s; wv[eidx][p] = ww; }
        }
    }
    __syncthreads();
    const int n1 = nz[0], n2 = nz[1];
    const size_t mbase = (size_t)m * Sn * Dn;
    const int dbase = chunk * 4096;
    for (int l = threadIdx.x * 4; l < 4096; l += 1024) {
        int d = dbase + l;
        float4 a = {0.f, 0.f, 0.f, 0.f};
        for (int j = 0; j < n1; ++j) {
            const f32x4 r = __builtin_nontemporal_load(
                (const f32x4*)(mem1 + mbase + (size_t)idx[0][j] * Dn + d));
            float ww = wv[0][j];
            a.x += ww * r.x; a.y += ww * r.y; a.z += ww * r.z; a.w += ww * r.w;
        }
        for (int j = 0; j < n2; ++j) {
            const f32x4 r = __builtin_nontemporal_load(
                (const f32x4*)(mem2 + mbase + (size_t)idx[1][j] * Dn + d));
            float ww = wv[1][j];
            a.x += ww * r.x; a.y += ww * r.y; a.z += ww * r.z; a.w += ww * r.w;
        }
        *(float4*)(acc + (size_t)(b * NUM_MEM + m) * Dn + d) = a;
    }
}

// ---------------- Phase E: acc (B,M,D) -> out (B,C,H,W) ---------------------
__global__ __launch_bounds__(256) void k_q2x(const float* __restrict__ acc,
                                             float* __restrict__ out) {
    const int h = blockIdx.x;          // 0..47
    const int b = blockIdx.y;          // 0..7
    const int gh = h >> 4, i = h & 15;
    __shared__ float tile[Cn * Hn];    // [c][w]
    for (int gw = 0; gw < 3; ++gw) {
        const float* ap = acc + (size_t)(b * NUM_MEM + gh * 3 + gw) * Dn + i * (WSZ * Cn);
        for (int l = threadIdx.x; l < WSZ * Cn; l += blockDim.x) {
            int j = l >> 8, c = l & 255;
            tile[c * Hn + gw * WSZ + j] = ap[l];
        }
    }
    __syncthreads();
    float* op = out + (size_t)b * Cn * Hn * Hn + (size_t)h * Hn;
    for (int o = threadIdx.x; o < Cn * Hn; o += blockDim.x) {
        int c = o / Hn, wcol = o - c * Hn;
        op[(size_t)c * Hn * Hn + wcol] = tile[o];
    }
}

extern "C" void kernel_launch(void* const* d_in, const int* in_sizes, int n_in,
                              void* d_out, int out_size, void* d_ws, size_t ws_size,
                              hipStream_t stream) {
    const float* x    = (const float*)d_in[0];
    const float* mem1 = (const float*)d_in[1];
    const float* mem2 = (const float*)d_in[2];
    float* out = (float*)d_out;

    // workspace: q/acc [B*M*D floats], w [2*B*M*S floats]
    float* q    = (float*)d_ws;
    float* wbuf = q + (size_t)Bn * NUM_MEM * Dn;
    // att partials live in d_out (4.7 MB of its 18.9 MB) — k_q2x overwrites all later
    float* ap   = (float*)d_out;

    k_x2q<<<dim3(Hn, Bn), 256, 0, stream>>>(x, q);
    k_att7<<<dim3(NDC, NUM_MEM, 16), 256, 0, stream>>>(q, mem1, mem2, ap);
    k_smax<<<2 * Bn * NUM_MEM, 128, 0, stream>>>(ap, wbuf);
    k_acc<<<dim3(16, NUM_MEM, Bn), 256, 0, stream>>>(wbuf, mem1, mem2, q /*acc*/);
    k_q2x<<<dim3(Hn, Bn), 256, 0, stream>>>(q, out);
}

// Round 9
// 195.816 us; speedup vs baseline: 1.1083x; 1.1083x over previous
//
#include <hip/hip_runtime.h>
#include <hip/hip_bf16.h>
#include <cstdint>

// Problem dims
#define Bn 8
#define Cn 256
#define Hn 48
#define NUM_MEM 9
#define WSZ 16
#define Sn 128
#define Dn 65536   // 16*16*256
#define KTOP 5
#define NDC 128    // d-chunks (512 floats each)

typedef float f32x4 __attribute__((ext_vector_type(4)));

// ---------------- Phase A: x (B,C,H,W) -> q (B,M,D), D = (i*16+j)*256 + c ----
__global__ __launch_bounds__(256) void k_x2q(const float* __restrict__ x,
                                             float* __restrict__ q) {
    const int h = blockIdx.x;          // 0..47
    const int b = blockIdx.y;          // 0..7
    const int gh = h >> 4, i = h & 15;
    __shared__ float tile[Cn * Hn];    // [c][w], 48KB
    const float* xp = x + (size_t)b * Cn * Hn * Hn + (size_t)h * Hn;
    for (int o = threadIdx.x; o < Cn * Hn; o += blockDim.x) {
        int c = o / Hn, w = o - c * Hn;
        tile[o] = xp[(size_t)c * Hn * Hn + w];
    }
    __syncthreads();
    for (int gw = 0; gw < 3; ++gw) {
        float* qp = q + (size_t)(b * NUM_MEM + gh * 3 + gw) * Dn + i * (WSZ * Cn);
        for (int l = threadIdx.x; l < WSZ * Cn; l += blockDim.x) {
            int j = l >> 8, c = l & 255;
            qp[l] = tile[c * Hn + gw * WSZ + j];
        }
    }
}

// ---------------- Phase B: single-shot partial dots, NON-TEMPORAL mem reads --
// Round-7 k_att6 verbatim (best measured: ~152 us). Single-shot blocks, 8 NT
// 1KB wave-loads issued up-front, q cached (L2 reuse across sgrp siblings).
// ap[dc][(e*8+b)*9+m][s] = partial dot over the 512-float chunk.
__global__ __launch_bounds__(256) void k_att6(const float* __restrict__ q,
                                              const float* __restrict__ mem1,
                                              const float* __restrict__ mem2,
                                              float* __restrict__ ap) {
    const int dc = blockIdx.x;     // 0..127
    const int mw = blockIdx.y;     // 0..8
    const int sg = blockIdx.z;     // 0..15
    const int e  = sg >> 3;
    const int lane = threadIdx.x & 63, wave = threadIdx.x >> 6;
    const int s0 = (sg & 7) * 16 + wave * 4;        // first of 4 s-rows

    const f32x4* mem4 = (const f32x4*)(e ? mem2 : mem1);
    const f32x4* q4   = (const f32x4*)q;
    const int off = dc * 128 + lane;                // f32x4 offset of slice 0

    // 8 independent non-temporal mem loads (4 rows x 2 slices), issued up-front
    f32x4 M[4][2];
#pragma unroll
    for (int r = 0; r < 4; ++r) {
        const f32x4* mp = mem4 + (size_t)(mw * Sn + s0 + r) * (Dn / 4) + off;
        M[r][0] = __builtin_nontemporal_load(mp);
        M[r][1] = __builtin_nontemporal_load(mp + 64);
    }

    float a[32];                                    // a[r*8+b]
#pragma unroll
    for (int i = 0; i < 32; ++i) a[i] = 0.f;

    // q in two b-halves to cap register pressure
#pragma unroll
    for (int half = 0; half < 2; ++half) {
        f32x4 Q[4][2];
#pragma unroll
        for (int b = 0; b < 4; ++b) {
            const f32x4* qp = q4 + (size_t)((half * 4 + b) * NUM_MEM + mw) * (Dn / 4) + off;
            Q[b][0] = qp[0];
            Q[b][1] = qp[64];
        }
#pragma unroll
        for (int r = 0; r < 4; ++r)
#pragma unroll
            for (int b = 0; b < 4; ++b) {
                const int bi = half * 4 + b;
                float acc = a[r * 8 + bi];
#pragma unroll
                for (int k = 0; k < 4; ++k)
                    acc += M[r][0][k] * Q[b][0][k] + M[r][1][k] * Q[b][1][k];
                a[r * 8 + bi] = acc;
            }
    }

    // fold-reduce: 32 values across 64 lanes (verified rounds 3-8)
#pragma unroll
    for (int k = 0; k < 5; ++k) {
        const int mk = 1 << k;
        const bool up = (lane & mk) != 0;
#pragma unroll
        for (int j = 0; j < (32 >> (k + 1)); ++j) {
            float lo = a[2 * j], hi = a[2 * j + 1];
            float mine = up ? hi : lo;
            float oth  = __shfl_xor(up ? lo : hi, mk, 64);
            a[j] = mine + oth;
        }
    }
    float rsum = a[0] + __shfl_xor(a[0], 32, 64);
    if (lane < 32) {
        const int b = lane & 7, r = (lane >> 3) & 3;
        ap[((size_t)dc * 144 + (size_t)(e * 8 + b) * 9 + mw) * Sn + (s0 + r)] = rsum;
    }
}

// ---------------- Phase C: nd-reduce + softmax + top-5 + shrink + L1 --------
__global__ __launch_bounds__(128) void k_smax(const float* __restrict__ ap,
                                              float* __restrict__ w) {
    const int row = blockIdx.x;        // 0..143  = (e*8+b)*9+m
    const int t = threadIdx.x;         // 0..127
    __shared__ float sf[Sn];
    __shared__ unsigned long long sk[Sn];

    float v = 0.f;
#pragma unroll 8
    for (int nd = 0; nd < NDC; ++nd)
        v += ap[((size_t)nd * 144 + row) * Sn + t];

    sf[t] = v; __syncthreads();
    for (int s = 64; s > 0; s >>= 1) { if (t < s) sf[t] = fmaxf(sf[t], sf[t + s]); __syncthreads(); }
    float mx = sf[0]; __syncthreads();

    float e = expf(v - mx);
    sf[t] = e; __syncthreads();
    for (int s = 64; s > 0; s >>= 1) { if (t < s) sf[t] += sf[t + s]; __syncthreads(); }
    float sum = sf[0]; __syncthreads();
    float y = e / sum;                 // softmax (y > 0)

    // 5 iterations of packed (value,index) argmax-with-exclusion -> 5th largest
    bool alive = true;
    float thres = 0.f;
    unsigned int ybits = __float_as_uint(y);   // y>0 -> bits monotonic
    for (int it = 0; it < KTOP; ++it) {
        sk[t] = alive ? ((((unsigned long long)ybits) << 32) | (unsigned)t) : 0ull;
        __syncthreads();
        for (int s = 64; s > 0; s >>= 1) {
            if (t < s) { if (sk[t + s] > sk[t]) sk[t] = sk[t + s]; }
            __syncthreads();
        }
        unsigned long long kmax = sk[0];
        __syncthreads();
        if ((unsigned)(kmax & 0xffffffffull) == (unsigned)t) alive = false;
        thres = __uint_as_float((unsigned)(kmax >> 32));
    }

    float d   = y - thres;
    float num = fmaxf(d, 0.f) * y;
    float yh  = num / (fabsf(d) + 1e-12f);     // exact reference formula

    sf[t] = yh; __syncthreads();
    for (int s = 64; s > 0; s >>= 1) { if (t < s) sf[t] += sf[t + s]; __syncthreads(); }
    float l1 = sf[0];
    w[(size_t)row * Sn + t] = yh / fmaxf(l1, 1e-12f);
}

// ---------------- Phase D+E fused: sparse accumulate -> direct out write ----
// block = (chunk, m, b). chunk's 4096 floats have constant i = chunk:
// d = (i*16+j)*256 + c -> out[b][c][gh*16+i][gw*16+j]. Accumulate into a
// 16x257-padded LDS tile (pad kills the 16-way bank conflict on the
// transposed read), then write 16-float j-bursts per c.
__global__ __launch_bounds__(256) void k_accout(const float* __restrict__ w,
                                                const float* __restrict__ mem1,
                                                const float* __restrict__ mem2,
                                                float* __restrict__ out) {
    const int chunk = blockIdx.x;      // 0..15  == i
    const int m     = blockIdx.y;      // 0..8
    const int b     = blockIdx.z;      // 0..7
    const int gh = m / 3, gw = m % 3;
    __shared__ int   nz[2];
    __shared__ int   idx[2][16];
    __shared__ float wv[2][16];
    __shared__ float lds[16 * 257];    // [j][c], padded
    if (threadIdx.x < 2) nz[threadIdx.x] = 0;
    __syncthreads();
    {
        int eidx = threadIdx.x >> 7;           // 0 or 1
        int s    = threadIdx.x & 127;
        float ww = w[((size_t)(eidx * Bn + b) * NUM_MEM + m) * Sn + s];
        if (ww != 0.f) {
            int p = atomicAdd(&nz[eidx], 1);
            if (p < 16) { idx[eidx][p] = s; wv[eidx][p] = ww; }
        }
    }
    __syncthreads();
    const int n1 = nz[0], n2 = nz[1];
    const size_t mbase = (size_t)m * Sn * Dn;
    const int dbase = chunk * 4096;
    for (int l = threadIdx.x * 4; l < 4096; l += 1024) {
        int d = dbase + l;
        float4 a = {0.f, 0.f, 0.f, 0.f};
        for (int j = 0; j < n1; ++j) {
            const f32x4 r = __builtin_nontemporal_load(
                (const f32x4*)(mem1 + mbase + (size_t)idx[0][j] * Dn + d));
            float ww = wv[0][j];
            a.x += ww * r.x; a.y += ww * r.y; a.z += ww * r.z; a.w += ww * r.w;
        }
        for (int j = 0; j < n2; ++j) {
            const f32x4 r = __builtin_nontemporal_load(
                (const f32x4*)(mem2 + mbase + (size_t)idx[1][j] * Dn + d));
            float ww = wv[1][j];
            a.x += ww * r.x; a.y += ww * r.y; a.z += ww * r.z; a.w += ww * r.w;
        }
        const int jj = l >> 8, cc = l & 255;   // 4 consecutive c, fixed j
        float* lp = &lds[jj * 257 + cc];
        lp[0] = a.x; lp[1] = a.y; lp[2] = a.z; lp[3] = a.w;
    }
    __syncthreads();
    const int row = gh * WSZ + chunk;
    float* op = out + (size_t)b * Cn * Hn * Hn + (size_t)row * Hn + gw * WSZ;
    for (int o = threadIdx.x; o < 4096; o += 256) {
        const int c = o >> 4, j = o & 15;
        op[(size_t)c * Hn * Hn + j] = lds[j * 257 + c];
    }
}

extern "C" void kernel_launch(void* const* d_in, const int* in_sizes, int n_in,
                              void* d_out, int out_size, void* d_ws, size_t ws_size,
                              hipStream_t stream) {
    const float* x    = (const float*)d_in[0];
    const float* mem1 = (const float*)d_in[1];
    const float* mem2 = (const float*)d_in[2];
    float* out = (float*)d_out;

    // workspace: q [B*M*D floats], w [2*B*M*S floats]
    float* q    = (float*)d_ws;
    float* wbuf = q + (size_t)Bn * NUM_MEM * Dn;
    // att partials live in d_out (9.4 MB of its 18.9 MB) — k_accout overwrites all later
    float* ap   = (float*)d_out;

    k_x2q<<<dim3(Hn, Bn), 256, 0, stream>>>(x, q);
    k_att6<<<dim3(NDC, NUM_MEM, 16), 256, 0, stream>>>(q, mem1, mem2, ap);
    k_smax<<<2 * Bn * NUM_MEM, 128, 0, stream>>>(ap, wbuf);
    k_accout<<<dim3(16, NUM_MEM, Bn), 256, 0, stream>>>(wbuf, mem1, mem2, out);
}

// Round 10
// 190.869 us; speedup vs baseline: 1.1371x; 1.0259x over previous
//
#include <hip/hip_runtime.h>
#include <hip/hip_bf16.h>
#include <cstdint>

// Problem dims
#define Bn 8
#define Cn 256
#define Hn 48
#define NUM_MEM 9
#define WSZ 16
#define Sn 128
#define Dn 65536   // 16*16*256
#define KTOP 5
#define NDC 128    // d-chunks (512 floats each)
#define CTH 46     // dc < CTH -> cached (L3-resident ~217MB); else NT stream

typedef float f32x4 __attribute__((ext_vector_type(4)));

// ---------------- Phase A: x (B,C,H,W) -> q (B,M,D), D = (i*16+j)*256 + c ----
__global__ __launch_bounds__(256) void k_x2q(const float* __restrict__ x,
                                             float* __restrict__ q) {
    const int h = blockIdx.x;          // 0..47
    const int b = blockIdx.y;          // 0..7
    const int gh = h >> 4, i = h & 15;
    __shared__ float tile[Cn * Hn];    // [c][w], 48KB
    const float* xp = x + (size_t)b * Cn * Hn * Hn + (size_t)h * Hn;
    for (int o = threadIdx.x; o < Cn * Hn; o += blockDim.x) {
        int c = o / Hn, w = o - c * Hn;
        tile[o] = xp[(size_t)c * Hn * Hn + w];
    }
    __syncthreads();
    for (int gw = 0; gw < 3; ++gw) {
        float* qp = q + (size_t)(b * NUM_MEM + gh * 3 + gw) * Dn + i * (WSZ * Cn);
        for (int l = threadIdx.x; l < WSZ * Cn; l += blockDim.x) {
            int j = l >> 8, c = l & 255;
            qp[l] = tile[c * Hn + gw * WSZ + j];
        }
    }
}

// ---------------- Phase B: single-shot partial dots, SPLIT temporal/NT ------
// Round-7 structure (best measured). One change: loads for dc < CTH use
// normal cached loads -> that 217MB slice of mem stays Infinity-Cache-resident
// across graph replays and is served from the cache path, concurrent with the
// NT HBM stream for dc >= CTH. Wave-uniform branch (dc = blockIdx.x).
// ap[dc][(e*8+b)*9+m][s] = partial dot over the 512-float chunk.
__global__ __launch_bounds__(256) void k_att8(const float* __restrict__ q,
                                              const float* __restrict__ mem1,
                                              const float* __restrict__ mem2,
                                              float* __restrict__ ap) {
    const int dc = blockIdx.x;     // 0..127
    const int mw = blockIdx.y;     // 0..8
    const int sg = blockIdx.z;     // 0..15
    const int e  = sg >> 3;
    const int lane = threadIdx.x & 63, wave = threadIdx.x >> 6;
    const int s0 = (sg & 7) * 16 + wave * 4;        // first of 4 s-rows

    const f32x4* mem4 = (const f32x4*)(e ? mem2 : mem1);
    const f32x4* q4   = (const f32x4*)q;
    const int off = dc * 128 + lane;                // f32x4 offset of slice 0

    // 8 independent mem loads (4 rows x 2 slices), issued up-front.
    // dc < CTH: cached (L3-resident slice). dc >= CTH: non-temporal stream.
    f32x4 M[4][2];
    if (dc < CTH) {
#pragma unroll
        for (int r = 0; r < 4; ++r) {
            const f32x4* mp = mem4 + (size_t)(mw * Sn + s0 + r) * (Dn / 4) + off;
            M[r][0] = mp[0];
            M[r][1] = mp[64];
        }
    } else {
#pragma unroll
        for (int r = 0; r < 4; ++r) {
            const f32x4* mp = mem4 + (size_t)(mw * Sn + s0 + r) * (Dn / 4) + off;
            M[r][0] = __builtin_nontemporal_load(mp);
            M[r][1] = __builtin_nontemporal_load(mp + 64);
        }
    }

    float a[32];                                    // a[r*8+b]
#pragma unroll
    for (int i = 0; i < 32; ++i) a[i] = 0.f;

    // q in two b-halves to cap register pressure (q always cached: real reuse)
#pragma unroll
    for (int half = 0; half < 2; ++half) {
        f32x4 Q[4][2];
#pragma unroll
        for (int b = 0; b < 4; ++b) {
            const f32x4* qp = q4 + (size_t)((half * 4 + b) * NUM_MEM + mw) * (Dn / 4) + off;
            Q[b][0] = qp[0];
            Q[b][1] = qp[64];
        }
#pragma unroll
        for (int r = 0; r < 4; ++r)
#pragma unroll
            for (int b = 0; b < 4; ++b) {
                const int bi = half * 4 + b;
                float acc = a[r * 8 + bi];
#pragma unroll
                for (int k = 0; k < 4; ++k)
                    acc += M[r][0][k] * Q[b][0][k] + M[r][1][k] * Q[b][1][k];
                a[r * 8 + bi] = acc;
            }
    }

    // fold-reduce: 32 values across 64 lanes (verified rounds 3-9)
#pragma unroll
    for (int k = 0; k < 5; ++k) {
        const int mk = 1 << k;
        const bool up = (lane & mk) != 0;
#pragma unroll
        for (int j = 0; j < (32 >> (k + 1)); ++j) {
            float lo = a[2 * j], hi = a[2 * j + 1];
            float mine = up ? hi : lo;
            float oth  = __shfl_xor(up ? lo : hi, mk, 64);
            a[j] = mine + oth;
        }
    }
    float rsum = a[0] + __shfl_xor(a[0], 32, 64);
    if (lane < 32) {
        const int b = lane & 7, r = (lane >> 3) & 3;
        ap[((size_t)dc * 144 + (size_t)(e * 8 + b) * 9 + mw) * Sn + (s0 + r)] = rsum;
    }
}

// ---------------- Phase C: nd-reduce + softmax + top-5 + shrink + L1 --------
__global__ __launch_bounds__(128) void k_smax(const float* __restrict__ ap,
                                              float* __restrict__ w) {
    const int row = blockIdx.x;        // 0..143  = (e*8+b)*9+m
    const int t = threadIdx.x;         // 0..127
    __shared__ float sf[Sn];
    __shared__ unsigned long long sk[Sn];

    float v = 0.f;
#pragma unroll 8
    for (int nd = 0; nd < NDC; ++nd)
        v += ap[((size_t)nd * 144 + row) * Sn + t];

    sf[t] = v; __syncthreads();
    for (int s = 64; s > 0; s >>= 1) { if (t < s) sf[t] = fmaxf(sf[t], sf[t + s]); __syncthreads(); }
    float mx = sf[0]; __syncthreads();

    float e = expf(v - mx);
    sf[t] = e; __syncthreads();
    for (int s = 64; s > 0; s >>= 1) { if (t < s) sf[t] += sf[t + s]; __syncthreads(); }
    float sum = sf[0]; __syncthreads();
    float y = e / sum;                 // softmax (y > 0)

    // 5 iterations of packed (value,index) argmax-with-exclusion -> 5th largest
    bool alive = true;
    float thres = 0.f;
    unsigned int ybits = __float_as_uint(y);   // y>0 -> bits monotonic
    for (int it = 0; it < KTOP; ++it) {
        sk[t] = alive ? ((((unsigned long long)ybits) << 32) | (unsigned)t) : 0ull;
        __syncthreads();
        for (int s = 64; s > 0; s >>= 1) {
            if (t < s) { if (sk[t + s] > sk[t]) sk[t] = sk[t + s]; }
            __syncthreads();
        }
        unsigned long long kmax = sk[0];
        __syncthreads();
        if ((unsigned)(kmax & 0xffffffffull) == (unsigned)t) alive = false;
        thres = __uint_as_float((unsigned)(kmax >> 32));
    }

    float d   = y - thres;
    float num = fmaxf(d, 0.f) * y;
    float yh  = num / (fabsf(d) + 1e-12f);     // exact reference formula

    sf[t] = yh; __syncthreads();
    for (int s = 64; s > 0; s >>= 1) { if (t < s) sf[t] += sf[t + s]; __syncthreads(); }
    float l1 = sf[0];
    w[(size_t)row * Sn + t] = yh / fmaxf(l1, 1e-12f);
}

// ---------------- Phase D+E fused: sparse accumulate -> direct out write ----
// block = (chunk, m, b); chunk == i. Same cached/NT split: chunk < 6 covers
// dc < 48 (the L3-resident slice), rest NT.
__global__ __launch_bounds__(256) void k_accout(const float* __restrict__ w,
                                                const float* __restrict__ mem1,
                                                const float* __restrict__ mem2,
                                                float* __restrict__ out) {
    const int chunk = blockIdx.x;      // 0..15  == i
    const int m     = blockIdx.y;      // 0..8
    const int b     = blockIdx.z;      // 0..7
    const int gh = m / 3, gw = m % 3;
    __shared__ int   nz[2];
    __shared__ int   idx[2][16];
    __shared__ float wv[2][16];
    __shared__ float lds[16 * 257];    // [j][c], padded
    if (threadIdx.x < 2) nz[threadIdx.x] = 0;
    __syncthreads();
    {
        int eidx = threadIdx.x >> 7;           // 0 or 1
        int s    = threadIdx.x & 127;
        float ww = w[((size_t)(eidx * Bn + b) * NUM_MEM + m) * Sn + s];
        if (ww != 0.f) {
            int p = atomicAdd(&nz[eidx], 1);
            if (p < 16) { idx[eidx][p] = s; wv[eidx][p] = ww; }
        }
    }
    __syncthreads();
    const int n1 = nz[0], n2 = nz[1];
    const size_t mbase = (size_t)m * Sn * Dn;
    const int dbase = chunk * 4096;
    const bool temporal = (chunk < 6);
    for (int l = threadIdx.x * 4; l < 4096; l += 1024) {
        int d = dbase + l;
        float4 a = {0.f, 0.f, 0.f, 0.f};
        if (temporal) {
            for (int j = 0; j < n1; ++j) {
                const f32x4 r = *(const f32x4*)(mem1 + mbase + (size_t)idx[0][j] * Dn + d);
                float ww = wv[0][j];
                a.x += ww * r.x; a.y += ww * r.y; a.z += ww * r.z; a.w += ww * r.w;
            }
            for (int j = 0; j < n2; ++j) {
                const f32x4 r = *(const f32x4*)(mem2 + mbase + (size_t)idx[1][j] * Dn + d);
                float ww = wv[1][j];
                a.x += ww * r.x; a.y += ww * r.y; a.z += ww * r.z; a.w += ww * r.w;
            }
        } else {
            for (int j = 0; j < n1; ++j) {
                const f32x4 r = __builtin_nontemporal_load(
                    (const f32x4*)(mem1 + mbase + (size_t)idx[0][j] * Dn + d));
                float ww = wv[0][j];
                a.x += ww * r.x; a.y += ww * r.y; a.z += ww * r.z; a.w += ww * r.w;
            }
            for (int j = 0; j < n2; ++j) {
                const f32x4 r = __builtin_nontemporal_load(
                    (const f32x4*)(mem2 + mbase + (size_t)idx[1][j] * Dn + d));
                float ww = wv[1][j];
                a.x += ww * r.x; a.y += ww * r.y; a.z += ww * r.z; a.w += ww * r.w;
            }
        }
        const int jj = l >> 8, cc = l & 255;   // 4 consecutive c, fixed j
        float* lp = &lds[jj * 257 + cc];
        lp[0] = a.x; lp[1] = a.y; lp[2] = a.z; lp[3] = a.w;
    }
    __syncthreads();
    const int row = gh * WSZ + chunk;
    float* op = out + (size_t)b * Cn * Hn * Hn + (size_t)row * Hn + gw * WSZ;
    for (int o = threadIdx.x; o < 4096; o += 256) {
        const int c = o >> 4, j = o & 15;
        op[(size_t)c * Hn * Hn + j] = lds[j * 257 + c];
    }
}

extern "C" void kernel_launch(void* const* d_in, const int* in_sizes, int n_in,
                              void* d_out, int out_size, void* d_ws, size_t ws_size,
                              hipStream_t stream) {
    const float* x    = (const float*)d_in[0];
    const float* mem1 = (const float*)d_in[1];
    const float* mem2 = (const float*)d_in[2];
    float* out = (float*)d_out;

    // workspace: q [B*M*D floats], w [2*B*M*S floats]
    float* q    = (float*)d_ws;
    float* wbuf = q + (size_t)Bn * NUM_MEM * Dn;
    // att partials live in d_out (9.4 MB of its 18.9 MB) — k_accout overwrites all later
    float* ap   = (float*)d_out;

    k_x2q<<<dim3(Hn, Bn), 256, 0, stream>>>(x, q);
    k_att8<<<dim3(NDC, NUM_MEM, 16), 256, 0, stream>>>(q, mem1, mem2, ap);
    k_smax<<<2 * Bn * NUM_MEM, 128, 0, stream>>>(ap, wbuf);
    k_accout<<<dim3(16, NUM_MEM, Bn), 256, 0, stream>>>(wbuf, mem1, mem2, out);
}